// Round 3
// baseline (494.149 us; speedup 1.0000x reference)
//
#include <hip/hip_runtime.h>
#include <cstdint>
#include <cstddef>

#define NSEQ 256
#define LRES 384
#define MDIM 256
#define NHEAD 8
#define CDIM 32
#define NL (NSEQ*LRES)          // 98304
#define SQC 0.17677669529663687f

// workspace element offsets (units: unsigned short / bf16 elements)
#define X_OFF    0u
#define WT_OFF   25165824u                 // NL*256
#define QKVG_OFF 25493504u                 // WT_OFF + 5*65536
#define PROJ_SZ  25165824u                 // NL*256 per projection
#define O_OFF    (QKVG_OFF + 4u*PROJ_SZ)   // 126156800

typedef __attribute__((ext_vector_type(8))) __bf16 bf16x8;
typedef __attribute__((ext_vector_type(4))) float f32x4;

__device__ __forceinline__ unsigned short f2bf(float f) {
  unsigned int u = __float_as_uint(f);
  u = (u + 0x7FFFu + ((u >> 16) & 1u)) >> 16;
  return (unsigned short)u;
}
__device__ __forceinline__ unsigned short f2bf_fast(float f) {
  return (unsigned short)((__float_as_uint(f) + 0x8000u) >> 16);
}
__device__ __forceinline__ float bf2f(unsigned short u){ return __uint_as_float(((unsigned int)u) << 16); }

// async global->LDS, 16B per lane; LDS dest = wave-uniform base + lane*16
__device__ __forceinline__ void gld16(const void* g, void* l) {
  __builtin_amdgcn_global_load_lds(
      (const __attribute__((address_space(1))) unsigned int*)g,
      (__attribute__((address_space(3))) unsigned int*)l, 16, 0, 0);
}

// ---------------- K1: LayerNorm -> x bf16 [NL, 256] ----------------
__global__ __launch_bounds__(256) void ln_kernel(const float* __restrict__ m,
    const float* __restrict__ gamma, const float* __restrict__ beta,
    unsigned short* __restrict__ x)
{
  int row  = blockIdx.x*4 + (threadIdx.x >> 6);
  int lane = threadIdx.x & 63;
  const float4 v = ((const float4*)(m + (size_t)row*MDIM))[lane];
  float s  = v.x + v.y + v.z + v.w;
  float ss = v.x*v.x + v.y*v.y + v.z*v.z + v.w*v.w;
  #pragma unroll
  for (int off = 32; off > 0; off >>= 1) {
    s  += __shfl_xor(s,  off, 64);
    ss += __shfl_xor(ss, off, 64);
  }
  float mu   = s * (1.f/MDIM);
  float var  = ss * (1.f/MDIM) - mu*mu;
  float rstd = rsqrtf(var + 1e-5f);
  float4 gm = ((const float4*)gamma)[lane];
  float4 bt = ((const float4*)beta)[lane];
  ushort4 pk;
  pk.x = f2bf((v.x - mu)*rstd*gm.x + bt.x);
  pk.y = f2bf((v.y - mu)*rstd*gm.y + bt.y);
  pk.z = f2bf((v.z - mu)*rstd*gm.z + bt.z);
  pk.w = f2bf((v.w - mu)*rstd*gm.w + bt.w);
  ((ushort4*)(x + (size_t)row*MDIM))[lane] = pk;
}

// ---------------- K1b: transpose+cast all 5 weights -> wT bf16 [p][n][k] ----------------
__global__ __launch_bounds__(256) void wtr_kernel(
    const float* __restrict__ W0, const float* __restrict__ W1,
    const float* __restrict__ W2, const float* __restrict__ W3,
    const float* __restrict__ W4, unsigned short* __restrict__ wT)
{
  int p = blockIdx.z;
  const float* W = (p==0)?W0:(p==1)?W1:(p==2)?W2:(p==3)?W3:W4;
  __shared__ float tile[32][33];
  int tx = threadIdx.x & 31, ty0 = threadIdx.x >> 5;
  int bi = blockIdx.x*32, bj = blockIdx.y*32;
  #pragma unroll
  for (int r = 0; r < 4; r++) {
    int ty = ty0 + r*8;
    tile[ty][tx] = W[(bi + ty)*MDIM + bj + tx];
  }
  __syncthreads();
  #pragma unroll
  for (int r = 0; r < 4; r++) {
    int ty = ty0 + r*8;
    wT[p*65536 + (bj + ty)*MDIM + bi + tx] = f2bf(tile[tx][ty]);
  }
}

// ---------------- K2: projections x @ [Wq|Wk|Wv|Wg] -> qkvg [p][NL][256] ----------------
// m97-style: 128x128 tile, BK=64, global_load_lds width 16, XOR bank swizzle
// folded into the per-lane GLOBAL address (LDS side of gld16 is rigid).
__global__ __launch_bounds__(256) void proj_kernel(const unsigned short* __restrict__ x,
    const unsigned short* __restrict__ wT, const float* __restrict__ bg,
    unsigned short* __restrict__ qkvg)
{
  __shared__ __align__(16) unsigned short As[128*64];
  __shared__ __align__(16) unsigned short Bs[128*64];
  const int bn = blockIdx.x, bm = blockIdx.y;
  const int tid = threadIdx.x;
  const int lane = tid & 63, wave = tid >> 6;
  const int ln = lane & 15, qd = lane >> 4;
  const int wm = (wave >> 1)*64, wn = (wave & 1)*64;
  const int Rbase = bm*128, Nbase = bn*128;

  // staging: row within 32-row issue-chunk, swizzled k-chunk (8 shorts = 16B)
  const int row0 = tid >> 3;                 // 0..31
  const int kc   = (tid & 7) ^ (row0 & 7);
  const unsigned short* aS = x + (size_t)(Rbase + row0)*256 + kc*8;
  const unsigned short* bS = wT + (size_t)(bn >> 1)*65536
                           + (size_t)((bn & 1)*128 + row0)*256 + kc*8;
  unsigned short* ldsA = As + wave*512;      // rows w*8.. ; + e*2048 per 32-row chunk
  unsigned short* ldsB = Bs + wave*512;

  f32x4 zero = {0.f,0.f,0.f,0.f};
  f32x4 acc[4][4];
  #pragma unroll
  for (int i=0;i<4;i++)
    #pragma unroll
    for (int j=0;j<4;j++) acc[i][j] = zero;

  const uint4* As4 = (const uint4*)As;
  const uint4* Bs4 = (const uint4*)Bs;

  for (int kk = 0; kk < 4; kk++) {
    #pragma unroll
    for (int e = 0; e < 4; e++) {
      gld16(aS + e*8192, ldsA + e*2048);
      gld16(bS + e*8192, ldsB + e*2048);
    }
    aS += 64; bS += 64;
    __syncthreads();
    #pragma unroll
    for (int kh = 0; kh < 2; kh++) {
      bf16x8 af[4], bfr[4];
      #pragma unroll
      for (int i=0;i<4;i++) {
        int r = wm + i*16 + ln;
        af[i] = __builtin_bit_cast(bf16x8, As4[r*8 + ((kh*4 + qd) ^ (r & 7))]);
      }
      #pragma unroll
      for (int j=0;j<4;j++) {
        int r = wn + j*16 + ln;
        bfr[j] = __builtin_bit_cast(bf16x8, Bs4[r*8 + ((kh*4 + qd) ^ (r & 7))]);
      }
      #pragma unroll
      for (int i=0;i<4;i++)
        #pragma unroll
        for (int j=0;j<4;j++)
          acc[i][j] = __builtin_amdgcn_mfma_f32_16x16x32_bf16(af[i], bfr[j], acc[i][j], 0, 0, 0);
    }
    __syncthreads();
  }

  const int p = Nbase >> 8;                  // block-uniform
  unsigned short* dstBase = qkvg + (size_t)p*PROJ_SZ;
  #pragma unroll
  for (int i=0;i<4;i++) {
    #pragma unroll
    for (int j=0;j<4;j++) {
      int Jc = Nbase + wn + j*16 + ln;
      int j256 = Jc & 255;
      #pragma unroll
      for (int r=0;r<4;r++) {
        int row = Rbase + wm + i*16 + qd*4 + r;
        float val = acc[i][j][r];
        if (p == 3) val = 1.f/(1.f + __expf(-(val + bg[j256])));
        dstBase[(size_t)row*256 + j256] = f2bf(val);
      }
    }
  }
}

// ---------------- K2b: transpose v [s*384+l][h*32+c] -> vt [l*8+h][c][s] ----------------
__global__ __launch_bounds__(256) void vtr_kernel(const unsigned short* __restrict__ v,
    unsigned short* __restrict__ vt)
{
  __shared__ unsigned short tile[32][33];
  const int st = blockIdx.x;                 // s-tile 0..7
  const int lh = blockIdx.y;                 // 0..3071
  const int l = lh >> 3, h = lh & 7;
  int tx = threadIdx.x & 31, ty0 = threadIdx.x >> 5;
  #pragma unroll
  for (int r=0;r<4;r++) {
    int ty = ty0 + r*8;
    tile[ty][tx] = v[((size_t)(st*32 + ty)*384 + l)*256 + h*32 + tx];   // [s_loc][c]
  }
  __syncthreads();
  #pragma unroll
  for (int r=0;r<4;r++) {
    int ty = ty0 + r*8;
    vt[(size_t)lh*8192 + ty*256 + st*32 + tx] = tile[tx][ty];           // [c][s]
  }
}

// ---------------- K3: attention per (l,h) — MFMA, barrier-free ----------------
__global__ __launch_bounds__(256, 2) void attn_kernel(
    const unsigned short* __restrict__ qkvg,
    const unsigned short* __restrict__ vt,
    unsigned short* __restrict__ o)
{
  const int l = blockIdx.x, h = blockIdx.y;
  const int tid = threadIdx.x;
  const int wave = tid >> 6, lane = tid & 63;
  const int ln = lane & 15, qd = lane >> 4;
  __shared__ __align__(16) unsigned short Pa[16384];   // 4 waves x 64 s x 64 t
  const uint4* qg = (const uint4*)qkvg;
  const uint4* kg = qg + (size_t)PROJ_SZ/8;
  const uint4* vg = (const uint4*)vt + (size_t)(l*8 + h)*1024;
  const int hq = h*4;
  const int s0 = wave*64;
  const int sw = ln & 7;

  // persistent Q B-frags: B[k=c][n=s]
  bf16x8 qf[4];
  #pragma unroll
  for (int nj=0;nj<4;nj++)
    qf[nj] = __builtin_bit_cast(bf16x8, qg[((size_t)(s0 + ln + 16*nj)*384 + l)*32 + hq + qd]);

  f32x4 zero = {0.f,0.f,0.f,0.f};
  f32x4 Oacc[2][4];
  #pragma unroll
  for (int mi=0;mi<2;mi++)
    #pragma unroll
    for (int nj=0;nj<4;nj++) Oacc[mi][nj] = zero;
  float rs[4] = {0.f,0.f,0.f,0.f};

  ushort4* Paw = (ushort4*)Pa;
  const uint4* Pa4 = (const uint4*)Pa;
  const int wbw = wave*1024;
  const int wb4 = wave*512;

  for (int c = 0; c < 4; c++) {
    bf16x8 kf[4];
    uint4 vfr[2][2];
    #pragma unroll
    for (int mi=0;mi<4;mi++)
      kf[mi] = __builtin_bit_cast(bf16x8, kg[((size_t)(c*64 + 16*mi + ln)*384 + l)*32 + hq + qd]);
    #pragma unroll
    for (int mi=0;mi<2;mi++)
      #pragma unroll
      for (int ks=0;ks<2;ks++)
        vfr[mi][ks] = vg[(ln + 16*mi)*32 + c*8 + ks*4 + qd];

    #pragma unroll
    for (int nj=0;nj<4;nj++) {
      f32x4 sv[4];
      #pragma unroll
      for (int mi=0;mi<4;mi++)
        sv[mi] = __builtin_amdgcn_mfma_f32_16x16x32_bf16(kf[mi], qf[nj], zero, 0, 0, 0);
      const int srow = ln + 16*nj;
      #pragma unroll
      for (int mi=0;mi<4;mi++) {
        float p0 = __expf(sv[mi][0]*SQC);
        float p1 = __expf(sv[mi][1]*SQC);
        float p2 = __expf(sv[mi][2]*SQC);
        float p3 = __expf(sv[mi][3]*SQC);
        rs[nj] += (p0+p1)+(p2+p3);
        ushort4 pk;
        pk.x = f2bf_fast(p0); pk.y = f2bf_fast(p1);
        pk.z = f2bf_fast(p2); pk.w = f2bf_fast(p3);
        Paw[wbw + srow*16 + (((2*mi + (qd>>1)) ^ sw) << 1) + (qd & 1)] = pk;
      }
    }
    #pragma unroll
    for (int ks=0;ks<2;ks++) {
      bf16x8 pf[4];
      #pragma unroll
      for (int nj=0;nj<4;nj++)
        pf[nj] = __builtin_bit_cast(bf16x8, Pa4[wb4 + (ln + 16*nj)*8 + ((4*ks + qd) ^ sw)]);
      #pragma unroll
      for (int mi=0;mi<2;mi++)
        #pragma unroll
        for (int nj=0;nj<4;nj++)
          Oacc[mi][nj] = __builtin_amdgcn_mfma_f32_16x16x32_bf16(
              __builtin_bit_cast(bf16x8, vfr[mi][ks]), pf[nj], Oacc[mi][nj], 0, 0, 0);
    }
  }

  #pragma unroll
  for (int nj=0;nj<4;nj++) {
    float r = rs[nj];
    r += __shfl_xor(r, 16, 64);
    r += __shfl_xor(r, 32, 64);
    rs[nj] = 1.f / r;
  }

  const unsigned short* gg = qkvg + 3u*(size_t)PROJ_SZ;
  #pragma unroll
  for (int mi=0;mi<2;mi++) {
    #pragma unroll
    for (int nj=0;nj<4;nj++) {
      const int sg = s0 + ln + 16*nj;
      const int c0 = 16*mi + 4*qd;
      const size_t rowOff = ((size_t)sg*384 + l)*256 + h*32 + c0;
      ushort4 gv = *(const ushort4*)(gg + rowOff);
      float inv = rs[nj];
      ushort4 ov;
      ov.x = f2bf(Oacc[mi][nj][0] * inv * bf2f(gv.x));
      ov.y = f2bf(Oacc[mi][nj][1] * inv * bf2f(gv.y));
      ov.z = f2bf(Oacc[mi][nj][2] * inv * bf2f(gv.z));
      ov.w = f2bf(Oacc[mi][nj][3] * inv * bf2f(gv.w));
      *(ushort4*)(o + rowOff) = ov;
    }
  }
}

// ---------------- K4: out = o @ Wo + bo (fp32), m97-style ----------------
__global__ __launch_bounds__(256) void out_kernel(const unsigned short* __restrict__ o,
    const unsigned short* __restrict__ wT, const float* __restrict__ bo,
    float* __restrict__ out)
{
  __shared__ __align__(16) unsigned short As[128*64];
  __shared__ __align__(16) unsigned short Bs[128*64];
  const int bn = blockIdx.x, bm = blockIdx.y;
  const int tid = threadIdx.x;
  const int lane = tid & 63, wave = tid >> 6;
  const int ln = lane & 15, qd = lane >> 4;
  const int wm = (wave >> 1)*64, wn = (wave & 1)*64;
  const int Rbase = bm*128, Nbase = bn*128;

  const int row0 = tid >> 3;
  const int kc   = (tid & 7) ^ (row0 & 7);
  const unsigned short* aS = o  + (size_t)(Rbase + row0)*256 + kc*8;
  const unsigned short* bS = wT + 4u*65536 + (size_t)(Nbase + row0)*256 + kc*8;
  unsigned short* ldsA = As + wave*512;
  unsigned short* ldsB = Bs + wave*512;

  f32x4 zero = {0.f,0.f,0.f,0.f};
  f32x4 acc[4][4];
  #pragma unroll
  for (int i=0;i<4;i++)
    #pragma unroll
    for (int j=0;j<4;j++) acc[i][j] = zero;

  const uint4* As4 = (const uint4*)As;
  const uint4* Bs4 = (const uint4*)Bs;

  for (int kk = 0; kk < 4; kk++) {
    #pragma unroll
    for (int e = 0; e < 4; e++) {
      gld16(aS + e*8192, ldsA + e*2048);
      gld16(bS + e*8192, ldsB + e*2048);
    }
    aS += 64; bS += 64;
    __syncthreads();
    #pragma unroll
    for (int kh = 0; kh < 2; kh++) {
      bf16x8 af[4], bfr[4];
      #pragma unroll
      for (int i=0;i<4;i++) {
        int r = wm + i*16 + ln;
        af[i] = __builtin_bit_cast(bf16x8, As4[r*8 + ((kh*4 + qd) ^ (r & 7))]);
      }
      #pragma unroll
      for (int j=0;j<4;j++) {
        int r = wn + j*16 + ln;
        bfr[j] = __builtin_bit_cast(bf16x8, Bs4[r*8 + ((kh*4 + qd) ^ (r & 7))]);
      }
      #pragma unroll
      for (int i=0;i<4;i++)
        #pragma unroll
        for (int j=0;j<4;j++)
          acc[i][j] = __builtin_amdgcn_mfma_f32_16x16x32_bf16(af[i], bfr[j], acc[i][j], 0, 0, 0);
    }
    __syncthreads();
  }

  #pragma unroll
  for (int i=0;i<4;i++) {
    #pragma unroll
    for (int j=0;j<4;j++) {
      int Jc = Nbase + wn + j*16 + ln;
      float bias = bo[Jc];
      #pragma unroll
      for (int r=0;r<4;r++) {
        int row = Rbase + wm + i*16 + qd*4 + r;
        out[(size_t)row*256 + Jc] = acc[i][j][r] + bias;
      }
    }
  }
}

extern "C" void kernel_launch(void* const* d_in, const int* in_sizes, int n_in,
                              void* d_out, int out_size, void* d_ws, size_t ws_size,
                              hipStream_t stream)
{
  const float* m     = (const float*)d_in[0];
  const float* gamma = (const float*)d_in[1];
  const float* beta  = (const float*)d_in[2];
  const float* Wq    = (const float*)d_in[3];
  const float* Wk    = (const float*)d_in[4];
  const float* Wv    = (const float*)d_in[5];
  const float* Wg    = (const float*)d_in[6];
  const float* bg    = (const float*)d_in[7];
  const float* Wo    = (const float*)d_in[8];
  const float* bo    = (const float*)d_in[9];
  float* out = (float*)d_out;
  unsigned short* ws   = (unsigned short*)d_ws;
  unsigned short* x    = ws + X_OFF;
  unsigned short* wT   = ws + WT_OFF;
  unsigned short* qkvg = ws + QKVG_OFF;
  unsigned short* ob   = ws + O_OFF;
  unsigned short* vnat = qkvg + 2u*(size_t)PROJ_SZ;

  hipLaunchKernelGGL(ln_kernel,   dim3(NL/4),      dim3(256), 0, stream, m, gamma, beta, x);
  hipLaunchKernelGGL(wtr_kernel,  dim3(8, 8, 5),   dim3(256), 0, stream, Wq, Wk, Wv, Wg, Wo, wT);
  hipLaunchKernelGGL(proj_kernel, dim3(8, 768),    dim3(256), 0, stream, x, wT, bg, qkvg);
  // x is dead after proj: reuse it for transposed V
  hipLaunchKernelGGL(vtr_kernel,  dim3(8, 3072),   dim3(256), 0, stream, vnat, x);
  hipLaunchKernelGGL(attn_kernel, dim3(384, 8),    dim3(256), 0, stream, qkvg, x, ob);
  hipLaunchKernelGGL(out_kernel,  dim3(2, 768),    dim3(256), 0, stream, ob, wT, bo, out);
}

// Round 4
// 441.239 us; speedup vs baseline: 1.1199x; 1.1199x over previous
//
#include <hip/hip_runtime.h>
#include <cstdint>
#include <cstddef>

#define NSEQ 256
#define LRES 384
#define MDIM 256
#define NHEAD 8
#define CDIM 32
#define NL (NSEQ*LRES)          // 98304
#define SQC 0.17677669529663687f

// workspace element offsets (units: unsigned short / bf16 elements)
#define X_OFF    0u
#define WT_OFF   25165824u                 // NL*256
#define QKVG_OFF 25493504u                 // WT_OFF + 5*65536
#define PROJ_SZ  25165824u                 // NL*256 per projection
#define O_OFF    (QKVG_OFF + 4u*PROJ_SZ)   // 126156800

typedef __attribute__((ext_vector_type(8))) __bf16 bf16x8;
typedef __attribute__((ext_vector_type(4))) float f32x4;

__device__ __forceinline__ unsigned short f2bf(float f) {
  unsigned int u = __float_as_uint(f);
  u = (u + 0x7FFFu + ((u >> 16) & 1u)) >> 16;
  return (unsigned short)u;
}
__device__ __forceinline__ unsigned short f2bf_fast(float f) {
  return (unsigned short)((__float_as_uint(f) + 0x8000u) >> 16);
}
__device__ __forceinline__ float bf2f(unsigned short u){ return __uint_as_float(((unsigned int)u) << 16); }

// async global->LDS, 16B per lane; LDS dest = wave-uniform base + lane*16
__device__ __forceinline__ void gld16(const void* g, void* l) {
  __builtin_amdgcn_global_load_lds(
      (const __attribute__((address_space(1))) unsigned int*)g,
      (__attribute__((address_space(3))) unsigned int*)l, 16, 0, 0);
}

// ---------------- K1: LayerNorm -> x bf16 [NL, 256] ----------------
__global__ __launch_bounds__(256) void ln_kernel(const float* __restrict__ m,
    const float* __restrict__ gamma, const float* __restrict__ beta,
    unsigned short* __restrict__ x)
{
  int row  = blockIdx.x*4 + (threadIdx.x >> 6);
  int lane = threadIdx.x & 63;
  const float4 v = ((const float4*)(m + (size_t)row*MDIM))[lane];
  float s  = v.x + v.y + v.z + v.w;
  float ss = v.x*v.x + v.y*v.y + v.z*v.z + v.w*v.w;
  #pragma unroll
  for (int off = 32; off > 0; off >>= 1) {
    s  += __shfl_xor(s,  off, 64);
    ss += __shfl_xor(ss, off, 64);
  }
  float mu   = s * (1.f/MDIM);
  float var  = ss * (1.f/MDIM) - mu*mu;
  float rstd = rsqrtf(var + 1e-5f);
  float4 gm = ((const float4*)gamma)[lane];
  float4 bt = ((const float4*)beta)[lane];
  ushort4 pk;
  pk.x = f2bf((v.x - mu)*rstd*gm.x + bt.x);
  pk.y = f2bf((v.y - mu)*rstd*gm.y + bt.y);
  pk.z = f2bf((v.z - mu)*rstd*gm.z + bt.z);
  pk.w = f2bf((v.w - mu)*rstd*gm.w + bt.w);
  ((ushort4*)(x + (size_t)row*MDIM))[lane] = pk;
}

// ---------------- K1b: transpose+cast all 5 weights -> wT bf16 [p][n][k] ----------------
__global__ __launch_bounds__(256) void wtr_kernel(
    const float* __restrict__ W0, const float* __restrict__ W1,
    const float* __restrict__ W2, const float* __restrict__ W3,
    const float* __restrict__ W4, unsigned short* __restrict__ wT)
{
  int p = blockIdx.z;
  const float* W = (p==0)?W0:(p==1)?W1:(p==2)?W2:(p==3)?W3:W4;
  __shared__ float tile[32][33];
  int tx = threadIdx.x & 31, ty0 = threadIdx.x >> 5;
  int bi = blockIdx.x*32, bj = blockIdx.y*32;
  #pragma unroll
  for (int r = 0; r < 4; r++) {
    int ty = ty0 + r*8;
    tile[ty][tx] = W[(bi + ty)*MDIM + bj + tx];
  }
  __syncthreads();
  #pragma unroll
  for (int r = 0; r < 4; r++) {
    int ty = ty0 + r*8;
    wT[p*65536 + (bj + ty)*MDIM + bi + tx] = f2bf(tile[tx][ty]);
  }
}

// ---------------- K2: projections, A-stationary ----------------
// Block = 64 M-rows. A (K=256) lives in registers (16 coalesced 64B loads/lane).
// Loop bn=0..7: full 64KB B-panel in LDS (chunk-XOR-swizzled), 2 barriers/bn,
// 64 MFMAs/wave between barriers. B(bn+1) staged after the post-compute
// barrier so its drain overlaps bn's epilogue stores.
__global__ __launch_bounds__(256, 2) void proj_kernel(const unsigned short* __restrict__ x,
    const unsigned short* __restrict__ wT, const float* __restrict__ bg,
    unsigned short* __restrict__ qkvg)
{
  __shared__ __align__(16) unsigned short Bs[128*256];   // 64KB
  const int tid = threadIdx.x;
  const int lane = tid & 63, wave = tid >> 6;
  const int ln = lane & 15, qd = lane >> 4;
  const int wm = (wave & 1)*32, wn = (wave >> 1)*64;
  const int Rbase = blockIdx.x*64;

  const int sro = lane >> 5;      // staging row offset 0..1
  const int sco = lane & 31;      // staging LDS chunk pos 0..31

  // stage B(0): p=0, nh=0
  #pragma unroll
  for (int e = 0; e < 16; e++) {
    int r = e*8 + wave*2 + sro;
    gld16(wT + (size_t)r*256 + ((sco ^ (r & 7))*8), Bs + (e*8 + wave*2)*256);
  }

  // A fragments in registers: afr[mi][kc], frag k-chunk index = kc*4 + qd
  bf16x8 afr[2][8];
  {
    const uint4* xg4 = (const uint4*)x;
    #pragma unroll
    for (int mi = 0; mi < 2; mi++) {
      size_t row = (size_t)(Rbase + wm + mi*16 + ln);
      #pragma unroll
      for (int kc = 0; kc < 8; kc++)
        afr[mi][kc] = __builtin_bit_cast(bf16x8, xg4[row*32 + kc*4 + qd]);
    }
  }

  const uint4* Bs4 = (const uint4*)Bs;
  f32x4 zero = {0.f,0.f,0.f,0.f};

  for (int bn = 0; bn < 8; bn++) {
    const int p  = bn >> 1;
    const int nh = (bn & 1)*128;
    f32x4 acc[2][4];
    #pragma unroll
    for (int i=0;i<2;i++)
      #pragma unroll
      for (int j=0;j<4;j++) acc[i][j] = zero;

    __syncthreads();               // B(bn) staged
    #pragma unroll
    for (int kc = 0; kc < 8; kc++) {
      bf16x8 bfr[4];
      #pragma unroll
      for (int j = 0; j < 4; j++) {
        int r = wn + j*16 + ln;
        bfr[j] = __builtin_bit_cast(bf16x8, Bs4[r*32 + ((kc*4 + qd) ^ (r & 7))]);
      }
      #pragma unroll
      for (int mi=0;mi<2;mi++)
        #pragma unroll
        for (int j=0;j<4;j++)
          acc[mi][j] = __builtin_amdgcn_mfma_f32_16x16x32_bf16(afr[mi][kc], bfr[j], acc[mi][j], 0, 0, 0);
    }
    __syncthreads();               // all reads of B(bn) done

    if (bn < 7) {                  // stage B(bn+1); drain overlaps epilogue
      int pn = (bn+1) >> 1, nhn = ((bn+1) & 1)*128;
      const unsigned short* wbase = wT + (size_t)pn*65536 + (size_t)nhn*256;
      #pragma unroll
      for (int e = 0; e < 16; e++) {
        int r = e*8 + wave*2 + sro;
        gld16(wbase + (size_t)r*256 + ((sco ^ (r & 7))*8), Bs + (e*8 + wave*2)*256);
      }
    }

    unsigned short* dstBase = qkvg + (size_t)p*PROJ_SZ;
    #pragma unroll
    for (int mi=0;mi<2;mi++) {
      #pragma unroll
      for (int j=0;j<4;j++) {
        int j256 = nh + wn + j*16 + ln;
        float bgv = (p == 3) ? bg[j256] : 0.f;
        #pragma unroll
        for (int r=0;r<4;r++) {
          int row = Rbase + wm + mi*16 + qd*4 + r;
          float val = acc[mi][j][r];
          if (p == 3) val = 1.f/(1.f + __expf(-(val + bgv)));
          dstBase[(size_t)row*256 + j256] = f2bf(val);
        }
      }
    }
  }
}

// ---------------- K2b: transpose v [s*384+l][h*32+c] -> vt [l*8+h][c][s] ----------------
__global__ __launch_bounds__(256) void vtr_kernel(const unsigned short* __restrict__ v,
    unsigned short* __restrict__ vt)
{
  __shared__ unsigned short tile[32][33];
  const int st = blockIdx.x;                 // s-tile 0..7
  const int lh = blockIdx.y;                 // 0..3071
  const int l = lh >> 3, h = lh & 7;
  int tx = threadIdx.x & 31, ty0 = threadIdx.x >> 5;
  #pragma unroll
  for (int r=0;r<4;r++) {
    int ty = ty0 + r*8;
    tile[ty][tx] = v[((size_t)(st*32 + ty)*384 + l)*256 + h*32 + tx];   // [s_loc][c]
  }
  __syncthreads();
  #pragma unroll
  for (int r=0;r<4;r++) {
    int ty = ty0 + r*8;
    vt[(size_t)lh*8192 + ty*256 + st*32 + tx] = tile[tx][ty];           // [c][s]
  }
}

// ---------------- K3: attention per (l,h) — MFMA, barrier-free ----------------
__global__ __launch_bounds__(256, 2) void attn_kernel(
    const unsigned short* __restrict__ qkvg,
    const unsigned short* __restrict__ vt,
    unsigned short* __restrict__ o)
{
  const int h = blockIdx.x, l = blockIdx.y;
  const int tid = threadIdx.x;
  const int wave = tid >> 6, lane = tid & 63;
  const int ln = lane & 15, qd = lane >> 4;
  __shared__ __align__(16) unsigned short Pa[16384];   // 4 waves x 64 s x 64 t
  const uint4* qg = (const uint4*)qkvg;
  const uint4* kg = qg + (size_t)PROJ_SZ/8;
  const uint4* vg = (const uint4*)vt + (size_t)(l*8 + h)*1024;
  const int hq = h*4;
  const int s0 = wave*64;
  const int sw = ln & 7;

  // persistent Q B-frags: B[k=c][n=s]
  bf16x8 qf[4];
  #pragma unroll
  for (int nj=0;nj<4;nj++)
    qf[nj] = __builtin_bit_cast(bf16x8, qg[((size_t)(s0 + ln + 16*nj)*384 + l)*32 + hq + qd]);

  f32x4 zero = {0.f,0.f,0.f,0.f};
  f32x4 Oacc[2][4];
  #pragma unroll
  for (int mi=0;mi<2;mi++)
    #pragma unroll
    for (int nj=0;nj<4;nj++) Oacc[mi][nj] = zero;
  float rs[4] = {0.f,0.f,0.f,0.f};

  ushort4* Paw = (ushort4*)Pa;
  const uint4* Pa4 = (const uint4*)Pa;
  const int wbw = wave*1024;
  const int wb4 = wave*512;

  for (int c = 0; c < 4; c++) {
    bf16x8 kf[4];
    uint4 vfr[2][2];
    #pragma unroll
    for (int mi=0;mi<4;mi++)
      kf[mi] = __builtin_bit_cast(bf16x8, kg[((size_t)(c*64 + 16*mi + ln)*384 + l)*32 + hq + qd]);
    #pragma unroll
    for (int mi=0;mi<2;mi++)
      #pragma unroll
      for (int ks=0;ks<2;ks++)
        vfr[mi][ks] = vg[(ln + 16*mi)*32 + c*8 + ks*4 + qd];

    #pragma unroll
    for (int nj=0;nj<4;nj++) {
      f32x4 sv[4];
      #pragma unroll
      for (int mi=0;mi<4;mi++)
        sv[mi] = __builtin_amdgcn_mfma_f32_16x16x32_bf16(kf[mi], qf[nj], zero, 0, 0, 0);
      const int srow = ln + 16*nj;
      #pragma unroll
      for (int mi=0;mi<4;mi++) {
        float p0 = __expf(sv[mi][0]*SQC);
        float p1 = __expf(sv[mi][1]*SQC);
        float p2 = __expf(sv[mi][2]*SQC);
        float p3 = __expf(sv[mi][3]*SQC);
        rs[nj] += (p0+p1)+(p2+p3);
        ushort4 pk;
        pk.x = f2bf_fast(p0); pk.y = f2bf_fast(p1);
        pk.z = f2bf_fast(p2); pk.w = f2bf_fast(p3);
        Paw[wbw + srow*16 + (((2*mi + (qd>>1)) ^ sw) << 1) + (qd & 1)] = pk;
      }
    }
    #pragma unroll
    for (int ks=0;ks<2;ks++) {
      bf16x8 pf[4];
      #pragma unroll
      for (int nj=0;nj<4;nj++)
        pf[nj] = __builtin_bit_cast(bf16x8, Pa4[wb4 + (ln + 16*nj)*8 + ((4*ks + qd) ^ sw)]);
      #pragma unroll
      for (int mi=0;mi<2;mi++)
        #pragma unroll
        for (int nj=0;nj<4;nj++)
          Oacc[mi][nj] = __builtin_amdgcn_mfma_f32_16x16x32_bf16(
              __builtin_bit_cast(bf16x8, vfr[mi][ks]), pf[nj], Oacc[mi][nj], 0, 0, 0);
    }
  }

  #pragma unroll
  for (int nj=0;nj<4;nj++) {
    float r = rs[nj];
    r += __shfl_xor(r, 16, 64);
    r += __shfl_xor(r, 32, 64);
    rs[nj] = 1.f / r;
  }

  const unsigned short* gg = qkvg + 3u*(size_t)PROJ_SZ;
  #pragma unroll
  for (int mi=0;mi<2;mi++) {
    #pragma unroll
    for (int nj=0;nj<4;nj++) {
      const int sg = s0 + ln + 16*nj;
      const int c0 = 16*mi + 4*qd;
      const size_t rowOff = ((size_t)sg*384 + l)*256 + h*32 + c0;
      ushort4 gv = *(const ushort4*)(gg + rowOff);
      float inv = rs[nj];
      ushort4 ov;
      ov.x = f2bf(Oacc[mi][nj][0] * inv * bf2f(gv.x));
      ov.y = f2bf(Oacc[mi][nj][1] * inv * bf2f(gv.y));
      ov.z = f2bf(Oacc[mi][nj][2] * inv * bf2f(gv.z));
      ov.w = f2bf(Oacc[mi][nj][3] * inv * bf2f(gv.w));
      *(ushort4*)(o + rowOff) = ov;
    }
  }
}

// ---------------- K4: out = o @ Wo + bo (fp32), A-stationary ----------------
__global__ __launch_bounds__(256, 2) void out_kernel(const unsigned short* __restrict__ o,
    const unsigned short* __restrict__ wT, const float* __restrict__ bo,
    float* __restrict__ out)
{
  __shared__ __align__(16) unsigned short Bs[128*256];   // 64KB
  const int tid = threadIdx.x;
  const int lane = tid & 63, wave = tid >> 6;
  const int ln = lane & 15, qd = lane >> 4;
  const int wm = (wave & 1)*32, wn = (wave >> 1)*64;
  const int Rbase = blockIdx.x*64;
  const unsigned short* wo = wT + 4u*65536;

  const int sro = lane >> 5;
  const int sco = lane & 31;

  #pragma unroll
  for (int e = 0; e < 16; e++) {
    int r = e*8 + wave*2 + sro;
    gld16(wo + (size_t)r*256 + ((sco ^ (r & 7))*8), Bs + (e*8 + wave*2)*256);
  }

  bf16x8 afr[2][8];
  {
    const uint4* og4 = (const uint4*)o;
    #pragma unroll
    for (int mi = 0; mi < 2; mi++) {
      size_t row = (size_t)(Rbase + wm + mi*16 + ln);
      #pragma unroll
      for (int kc = 0; kc < 8; kc++)
        afr[mi][kc] = __builtin_bit_cast(bf16x8, og4[row*32 + kc*4 + qd]);
    }
  }

  const uint4* Bs4 = (const uint4*)Bs;
  f32x4 zero = {0.f,0.f,0.f,0.f};

  for (int bn = 0; bn < 2; bn++) {
    const int nh = bn*128;
    f32x4 acc[2][4];
    #pragma unroll
    for (int i=0;i<2;i++)
      #pragma unroll
      for (int j=0;j<4;j++) acc[i][j] = zero;

    __syncthreads();
    #pragma unroll
    for (int kc = 0; kc < 8; kc++) {
      bf16x8 bfr[4];
      #pragma unroll
      for (int j = 0; j < 4; j++) {
        int r = wn + j*16 + ln;
        bfr[j] = __builtin_bit_cast(bf16x8, Bs4[r*32 + ((kc*4 + qd) ^ (r & 7))]);
      }
      #pragma unroll
      for (int mi=0;mi<2;mi++)
        #pragma unroll
        for (int j=0;j<4;j++)
          acc[mi][j] = __builtin_amdgcn_mfma_f32_16x16x32_bf16(afr[mi][kc], bfr[j], acc[mi][j], 0, 0, 0);
    }
    __syncthreads();

    if (bn < 1) {
      const unsigned short* wbase = wo + 128u*256;
      #pragma unroll
      for (int e = 0; e < 16; e++) {
        int r = e*8 + wave*2 + sro;
        gld16(wbase + (size_t)r*256 + ((sco ^ (r & 7))*8), Bs + (e*8 + wave*2)*256);
      }
    }

    #pragma unroll
    for (int mi=0;mi<2;mi++) {
      #pragma unroll
      for (int j=0;j<4;j++) {
        int col = nh + wn + j*16 + ln;
        float bias = bo[col];
        #pragma unroll
        for (int r=0;r<4;r++) {
          int row = Rbase + wm + mi*16 + qd*4 + r;
          out[(size_t)row*256 + col] = acc[mi][j][r] + bias;
        }
      }
    }
  }
}

extern "C" void kernel_launch(void* const* d_in, const int* in_sizes, int n_in,
                              void* d_out, int out_size, void* d_ws, size_t ws_size,
                              hipStream_t stream)
{
  const float* m     = (const float*)d_in[0];
  const float* gamma = (const float*)d_in[1];
  const float* beta  = (const float*)d_in[2];
  const float* Wq    = (const float*)d_in[3];
  const float* Wk    = (const float*)d_in[4];
  const float* Wv    = (const float*)d_in[5];
  const float* Wg    = (const float*)d_in[6];
  const float* bg    = (const float*)d_in[7];
  const float* Wo    = (const float*)d_in[8];
  const float* bo    = (const float*)d_in[9];
  float* out = (float*)d_out;
  unsigned short* ws   = (unsigned short*)d_ws;
  unsigned short* x    = ws + X_OFF;
  unsigned short* wT   = ws + WT_OFF;
  unsigned short* qkvg = ws + QKVG_OFF;
  unsigned short* ob   = ws + O_OFF;
  unsigned short* vnat = qkvg + 2u*(size_t)PROJ_SZ;

  hipLaunchKernelGGL(ln_kernel,   dim3(NL/4),      dim3(256), 0, stream, m, gamma, beta, x);
  hipLaunchKernelGGL(wtr_kernel,  dim3(8, 8, 5),   dim3(256), 0, stream, Wq, Wk, Wv, Wg, Wo, wT);
  hipLaunchKernelGGL(proj_kernel, dim3(1536),      dim3(256), 0, stream, x, wT, bg, qkvg);
  // x is dead after proj: reuse it for transposed V
  hipLaunchKernelGGL(vtr_kernel,  dim3(8, 3072),   dim3(256), 0, stream, vnat, x);
  hipLaunchKernelGGL(attn_kernel, dim3(8, 384),    dim3(256), 0, stream, qkvg, x, ob);
  hipLaunchKernelGGL(out_kernel,  dim3(1536),      dim3(256), 0, stream, ob, wT, bo, out);
}